// Round 8
// baseline (405.273 us; speedup 1.0000x reference)
//
#include <hip/hip_runtime.h>

// SetEq4to4: out[n,so,i,j,k,l] = sum over 69 basis ops (A,B) + bias.
// n=2, d=8, so=8, N=32, basis=69.
//
// Pipeline (memset + 3 regular launches):
//   MS hipMemsetAsync: zero red2_23/red1 accum + T2f/T1f tables + counters.
//   KR k_red3 (1024 blk x 512 thr): x -> r012,r013,r023 (plane) / r123 (col),
//              all red2/red1 (direct + atomicAdd), AND the T2f/T1f channel-mix
//              fold via last-arriver counters:
//                per-(n,i) last-of-8d:  T2f += a2 in {01,02,03} row fold
//                per-(n,j) last-of-8d:  T2f += a2 in {12,13} row fold
//                per-n last-of-512:     T2f += a2=23 part; T1f = full fold
//              (no spinning: last arriver does the work itself)
//   KM k_mix  (1024 blk x 256 thr): U3[b] = mixed red3 + T2f/T1f table reads
//              + bias.  v[4][8] coalesced, VGPR-lean, 16 waves/CU.
//   K6 k_final (XCD-chunked swizzle): out = sum_d c68*x + U012+U013+U023+U123

constexpr size_t R3SZ  = 524288;   // per-a: 16 nd * 32768
constexpr size_t R2SZ  = 16384;    // per-b2: 16 nd * 1024
constexpr size_t R1SZ  = 512;      // per-b1: 16 nd * 32
constexpr size_t R3OFF = 0;
constexpr size_t R2OFF = R3OFF + 4 * R3SZ;   // red2: (01)(02)(03)(12)(13)(23)
constexpr size_t R1OFF = R2OFF + 6 * R2SZ;   // red1: (0)(1)(2)(3)
constexpr size_t T2OFF = R1OFF + 4 * R1SZ;   // T2f: 6 tables
constexpr size_t T1OFF = T2OFF + 6 * R2SZ;   // T1f: 4 tables
constexpr size_t CTROFF= T1OFF + 4 * R1SZ;   // ints: [0..63]=(n,i), [64..127]=(n,j), [128..129]=n
constexpr size_t U3OFF = CTROFF + 256;
// total ws floats: U3OFF + 4*R3SZ = 4395264 (~17.6 MiB)
// memset region: [R2OFF+5*R2SZ, U3OFF) = 119040 floats = 476160 B

// ---------------- KR: rank-3 reductions + red2/red1 + T2f/T1f folds ----------------
__global__ __launch_bounds__(512) void k_red3(const float* __restrict__ x,
                                              const float* __restrict__ coefs,
                                              float* __restrict__ ws) {
    __shared__ float4 cp[32][4][8];   // [j][k-octet][l4] col partials (16 KiB)
    __shared__ float  b012[1024];     // [j][k] row sums (4 KiB)
    __shared__ float4 a2[256];        // park buffer (4 KiB)
    __shared__ float  c23[8][6][8];   // [d][b2][so] coef slice for n-fold (1.5 KiB)
    __shared__ int    sRow, sN;
    const int bid  = blockIdx.x;
    const int t    = threadIdx.x;
    const int half = t >> 8;          // parity of the loop axis handled by this half
    const int tt   = t & 255;
    const int k    = tt >> 3;         // k index owned by this thread
    const int l4   = tt & 7;          // l-quad owned by this thread

    int rowIdx, nIdx, rowP;           // fold identifiers
    if (bid < 512) {
        // -------- plane blocks: fixed (nd, i), loop over j --------
        const int i    = bid & 31;
        const int nd   = bid >> 5;
        const int w4   = (t >> 6) & 3;   // which k-octet this wave covers
        const int lane = t & 63;
        rowIdx = (nd >> 3) * 32 + i; nIdx = nd >> 3; rowP = i;
        const float* xp = x + ((size_t)nd << 20) + ((size_t)i << 15) + k * 32 + l4 * 4;
        float4 acc = {0.f, 0.f, 0.f, 0.f};           // r023[i,k,l] accumulator
        #pragma unroll
        for (int it = 0; it < 16; ++it) {
            const int j = it * 2 + half;
            float4 v = *(const float4*)(xp + j * 1024);
            acc.x += v.x; acc.y += v.y; acc.z += v.z; acc.w += v.w;
            // r012[i,j,k] = sum over l: hsum + butterfly over lane bits 0..2
            float h = v.x + v.y + v.z + v.w;
            h += __shfl_xor(h, 1); h += __shfl_xor(h, 2); h += __shfl_xor(h, 4);
            if (l4 == 0) b012[j * 32 + k] = h;
            // col partials over this wave's 8 k's: butterfly over lane bits 3..5
            v.x += __shfl_xor(v.x, 8);  v.y += __shfl_xor(v.y, 8);
            v.z += __shfl_xor(v.z, 8);  v.w += __shfl_xor(v.w, 8);
            v.x += __shfl_xor(v.x, 16); v.y += __shfl_xor(v.y, 16);
            v.z += __shfl_xor(v.z, 16); v.w += __shfl_xor(v.w, 16);
            v.x += __shfl_xor(v.x, 32); v.y += __shfl_xor(v.y, 32);
            v.z += __shfl_xor(v.z, 32); v.w += __shfl_xor(v.w, 32);
            if (lane < 8) cp[j][w4][lane] = v;
        }
        if (half == 1) a2[tt] = acc;                 // park for r023 combine
        __syncthreads();
        const size_t base = ((size_t)nd << 15) + ((size_t)i << 10);
        *(float2*)(ws + R3OFF + base + 2 * t) = *(const float2*)(b012 + 2 * t);
        if (half == 0) {
            // r013[i,j,l]: combine the 4 k-octet partials
            const int j = tt >> 3, lj = tt & 7;
            float4 s0 = cp[j][0][lj], s1 = cp[j][1][lj];
            float4 s2 = cp[j][2][lj], s3 = cp[j][3][lj];
            float4 s;
            s.x = s0.x + s1.x + s2.x + s3.x;
            s.y = s0.y + s1.y + s2.y + s3.y;
            s.z = s0.z + s1.z + s2.z + s3.z;
            s.w = s0.w + s1.w + s2.w + s3.w;
            *(float4*)(ws + R3OFF + R3SZ + base + j * 32 + lj * 4) = s;
            // r023[i,k,l]: merge the two j-parity halves
            float4 b = a2[tt];
            a2[tt] = s;                              // a2 flat view = r013[j][l]
            acc.x += b.x; acc.y += b.y; acc.z += b.z; acc.w += b.w;
            *(float4*)(ws + R3OFF + 2 * R3SZ + base + k * 32 + l4 * 4) = acc;
            // red2_23[k,l] += r023[i,k,l]  (region zeroed by stream-head memset)
            float* r23 = ws + R2OFF + 5 * R2SZ + (size_t)nd * 1024 + k * 32 + l4 * 4;
            atomicAdd(r23 + 0, acc.x); atomicAdd(r23 + 1, acc.y);
            atomicAdd(r23 + 2, acc.z); atomicAdd(r23 + 3, acc.w);
        }
        __syncthreads();
        // epilogue 2: red2 (01)(02)(03) + red1 (0)(2)(3) for this i
        const size_t r2b = (size_t)nd * 1024 + (size_t)i * 32;
        if (t < 32) {
            float s = 0.f;
            #pragma unroll
            for (int kk = 0; kk < 32; ++kk) s += b012[t * 32 + ((kk + t) & 31)];
            ws[R2OFF + 0 * R2SZ + r2b + t] = s;
            float r = s;
            r += __shfl_xor(r, 1);  r += __shfl_xor(r, 2);  r += __shfl_xor(r, 4);
            r += __shfl_xor(r, 8);  r += __shfl_xor(r, 16);
            if (t == 0) ws[R1OFF + 0 * R1SZ + (size_t)nd * 32 + i] = r;
        } else if (t < 64) {
            const int kc = t - 32;
            float s = 0.f;
            #pragma unroll
            for (int j = 0; j < 32; ++j) s += b012[j * 32 + kc];
            ws[R2OFF + 1 * R2SZ + r2b + kc] = s;
            atomicAdd(ws + R1OFF + 2 * R1SZ + (size_t)nd * 32 + kc, s);
        } else if (t < 96) {
            const int l = t - 64;
            const float* af = (const float*)a2;
            float s = 0.f;
            #pragma unroll
            for (int j = 0; j < 32; ++j) s += af[j * 32 + l];
            ws[R2OFF + 2 * R2SZ + r2b + l] = s;
            atomicAdd(ws + R1OFF + 3 * R1SZ + (size_t)nd * 32 + l, s);
        }
    } else {
        // -------- col blocks: fixed (nd, j), loop over i --------
        const int bb = bid - 512;
        const int j  = bb & 31;
        const int nd = bb >> 5;
        rowIdx = 64 + (nd >> 3) * 32 + j; nIdx = nd >> 3; rowP = j;
        const float* xp = x + ((size_t)nd << 20) + (size_t)j * 1024 + (size_t)tt * 4;
        float4 acc = {0.f, 0.f, 0.f, 0.f};
        #pragma unroll
        for (int it = 0; it < 16; ++it) {
            const int i = it * 2 + half;
            float4 v = *(const float4*)(xp + ((size_t)i << 15));
            acc.x += v.x; acc.y += v.y; acc.z += v.z; acc.w += v.w;
        }
        if (half == 1) a2[tt] = acc;
        __syncthreads();
        const size_t r2b = (size_t)nd * 1024 + (size_t)j * 32;
        if (half == 0) {
            float4 b = a2[tt];
            acc.x += b.x; acc.y += b.y; acc.z += b.z; acc.w += b.w;
            *(float4*)(ws + R3OFF + 3 * R3SZ + ((size_t)nd << 15)
                       + ((size_t)j << 10) + tt * 4) = acc;   // r123[j][k][l]
            // red2_12[j][k] = sum_l r123
            float h = acc.x + acc.y + acc.z + acc.w;
            h += __shfl_xor(h, 1); h += __shfl_xor(h, 2); h += __shfl_xor(h, 4);
            if ((t & 7) == 0) {
                ws[R2OFF + 3 * R2SZ + r2b + k] = h;
                b012[k] = h;                          // park for red1_1 reduce
            }
            // red2_13[j][l] = sum_k r123
            float4 c2 = acc;
            c2.x += __shfl_xor(c2.x, 8);  c2.y += __shfl_xor(c2.y, 8);
            c2.z += __shfl_xor(c2.z, 8);  c2.w += __shfl_xor(c2.w, 8);
            c2.x += __shfl_xor(c2.x, 16); c2.y += __shfl_xor(c2.y, 16);
            c2.z += __shfl_xor(c2.z, 16); c2.w += __shfl_xor(c2.w, 16);
            c2.x += __shfl_xor(c2.x, 32); c2.y += __shfl_xor(c2.y, 32);
            c2.z += __shfl_xor(c2.z, 32); c2.w += __shfl_xor(c2.w, 32);
            if ((t & 63) < 8) cp[0][t >> 6][t & 63] = c2;
        }
        __syncthreads();
        if (t < 8) {
            float4 s0 = cp[0][0][t], s1 = cp[0][1][t];
            float4 s2 = cp[0][2][t], s3 = cp[0][3][t];
            float4 s;
            s.x = s0.x + s1.x + s2.x + s3.x;
            s.y = s0.y + s1.y + s2.y + s3.y;
            s.z = s0.z + s1.z + s2.z + s3.z;
            s.w = s0.w + s1.w + s2.w + s3.w;
            *(float4*)(ws + R2OFF + 4 * R2SZ + r2b + t * 4) = s;
        }
        if (t < 32) {
            float r = b012[t];
            r += __shfl_xor(r, 1);  r += __shfl_xor(r, 2);  r += __shfl_xor(r, 4);
            r += __shfl_xor(r, 8);  r += __shfl_xor(r, 16);
            if (t == 0) ws[R1OFF + 1 * R1SZ + (size_t)nd * 32 + j] = r;
        }
    }

    // ---------------- completion-tail folds (no spinning) ----------------
    __syncthreads();                       // drains all this block's mem ops
    if (t == 0) {
        __threadfence();                   // device-scope release of our writes
        int* ctr = (int*)(ws + CTROFF);
        sRow = (__hip_atomic_fetch_add(&ctr[rowIdx], 1, __ATOMIC_ACQ_REL,
                                       __HIP_MEMORY_SCOPE_AGENT) == 7);
        sN   = (__hip_atomic_fetch_add(&ctr[128 + nIdx], 1, __ATOMIC_ACQ_REL,
                                       __HIP_MEMORY_SCOPE_AGENT) == 511);
    }
    __syncthreads();
    const int n = nIdx;
    if (sRow) {
        // row fold: a2 in {0,1,2} (plane rows) or {3,4} (col rows) at pq=(rowP,q)
        const int a2lo = (bid < 512) ? 0 : 3;
        const int a2hi = (bid < 512) ? 3 : 5;
        for (int id = t; id < 1536; id += 512) {
            const int b2 = id >> 8, so = (id >> 5) & 7, q = id & 31;
            float s = 0.f;
            for (int a = a2lo; a < a2hi; ++a)
                #pragma unroll
                for (int d = 0; d < 8; ++d)
                    s += coefs[(d * 8 + so) * 69 + 16 + a * 6 + b2]
                         * ws[R2OFF + (size_t)a * R2SZ + (size_t)(n * 8 + d) * 1024
                              + rowP * 32 + q];
            atomicAdd(ws + T2OFF + (size_t)b2 * R2SZ + (size_t)(n * 8 + so) * 1024
                      + rowP * 32 + q, s);
        }
    }
    if (sN) {
        // n fold: a2=23 part of T2f + full T1f (red2_23/red1 complete for this n)
        for (int idx = t; idx < 384; idx += 512) {
            const int d = idx / 48, rr = idx - d * 48, b2 = rr >> 3, so = rr & 7;
            c23[d][b2][so] = coefs[(d * 8 + so) * 69 + 46 + b2];
        }
        __syncthreads();
        #pragma unroll
        for (int m = 0; m < 2; ++m) {
            const int pq = t + m * 512;
            float r23[8];
            #pragma unroll
            for (int d = 0; d < 8; ++d)
                r23[d] = ws[R2OFF + 5 * R2SZ + (size_t)(n * 8 + d) * 1024 + pq];
            #pragma unroll
            for (int b2 = 0; b2 < 6; ++b2)
                #pragma unroll
                for (int so = 0; so < 8; ++so) {
                    float s = 0.f;
                    #pragma unroll
                    for (int d = 0; d < 8; ++d) s += c23[d][b2][so] * r23[d];
                    atomicAdd(ws + T2OFF + (size_t)b2 * R2SZ
                              + (size_t)(n * 8 + so) * 1024 + pq, s);
                }
        }
        for (int id = t; id < 1024; id += 512) {
            const int b1 = id >> 8, so = (id >> 5) & 7, p = id & 31;
            float s = 0.f;
            for (int a1 = 0; a1 < 4; ++a1)
                #pragma unroll
                for (int d = 0; d < 8; ++d)
                    s += coefs[(d * 8 + so) * 69 + a1 * 4 + b1]
                         * ws[R1OFF + (size_t)a1 * R1SZ + (size_t)(n * 8 + d) * 32 + p];
            ws[T1OFF + (size_t)b1 * R1SZ + (size_t)(n * 8 + so) * 32 + p] = s;
        }
    }
}

// ---------------- KM: slim U3 mix from completed T tables ----------------
__global__ __launch_bounds__(256) void k_mix(const float* __restrict__ coefs,
                                             const float* __restrict__ bias,
                                             float* __restrict__ ws) {
    __shared__ float csm[2][8][16];    // [so2][d][a*4+b] main-mix coefs (1 KiB)
    const int tt  = threadIdx.x;
    const int blk = blockIdx.x;        // 1024 = n(1) | sop(2) | cb(7)
    const int cb  = blk & 127;
    const int sop = (blk >> 7) & 3;
    const int n   = blk >> 9;
    {
        const int so2 = tt >> 7, d = (tt >> 4) & 7, ab = tt & 15;
        csm[so2][d][ab] = coefs[(d * 8 + sop * 2 + so2) * 69 + 52 + ab];
    }
    const int c  = cb * 256 + tt;
    const int p1 = c >> 10, p2 = (c >> 5) & 31, p3 = c & 31;
    float v[4][8];
    #pragma unroll
    for (int a = 0; a < 4; ++a)
        #pragma unroll
        for (int d = 0; d < 8; ++d)
            v[a][d] = ws[R3OFF + (size_t)a * R3SZ + (size_t)(n * 8 + d) * 32768 + c];
    __syncthreads();
    const float* T2 = ws + T2OFF;
    const float* T1 = ws + T1OFF;
    #pragma unroll
    for (int b = 0; b < 4; ++b) {
        #pragma unroll
        for (int so2 = 0; so2 < 2; ++so2) {
            const int so = sop * 2 + so2;
            float s = 0.f;
            #pragma unroll
            for (int a = 0; a < 4; ++a)
                #pragma unroll
                for (int d = 0; d < 8; ++d)
                    s += csm[so2][d][a * 4 + b] * v[a][d];
            const size_t nso = (size_t)(n * 8 + so);
            if (b == 0) {
                s += T2[0 * R2SZ + nso * 1024 + p1 * 32 + p2];
                s += T2[1 * R2SZ + nso * 1024 + p1 * 32 + p3];
                s += T2[3 * R2SZ + nso * 1024 + p2 * 32 + p3];
                s += T1[0 * R1SZ + nso * 32 + p1];
                s += T1[1 * R1SZ + nso * 32 + p2];
                s += T1[2 * R1SZ + nso * 32 + p3];
                s += bias[so];
            } else if (b == 1) {
                s += T2[2 * R2SZ + nso * 1024 + p1 * 32 + p3];
                s += T2[4 * R2SZ + nso * 1024 + p2 * 32 + p3];
                s += T1[3 * R1SZ + nso * 32 + p3];
            } else if (b == 2) {
                s += T2[5 * R2SZ + nso * 1024 + p2 * 32 + p3];
            }
            ws[U3OFF + (size_t)b * R3SZ + nso * 32768 + c] = s;
        }
    }
}

// ---------------- K6: final broadcast-add + s=4 channel mix ----------------
__global__ __launch_bounds__(256) void k_final(const float* __restrict__ x,
                                               const float* __restrict__ coefs,
                                               const float* __restrict__ ws,
                                               float* __restrict__ out) {
    __shared__ float c68[64];
    if (threadIdx.x < 64) c68[threadIdx.x] = coefs[threadIdx.x * 69 + 68];
    __syncthreads();
    // XCD-chunked bijective swizzle (2048 % 8 == 0)
    const int rb = blockIdx.x;
    const int b  = ((rb & 7) << 8) | (rb >> 3);
    const int j = b & 31;
    const int i = (b >> 5) & 31;
    const int n = b >> 10;
    const int t = threadIdx.x;
    const int k = t >> 3, lq = t & 7;

    float4 xv[8];
    const float* xb = x + ((size_t)n << 23) + ((size_t)i << 15) + j * 1024 + k * 32 + lq * 4;
    #pragma unroll
    for (int d = 0; d < 8; ++d) xv[d] = *(const float4*)(xb + ((size_t)d << 20));

    const float* U = ws + U3OFF;
    const size_t c012 = (size_t)i * 1024 + j * 32 + k;
    const size_t c013 = (size_t)i * 1024 + j * 32 + lq * 4;
    const size_t c023 = (size_t)i * 1024 + k * 32 + lq * 4;
    const size_t c123 = (size_t)j * 1024 + k * 32 + lq * 4;

    #pragma unroll
    for (int so = 0; so < 8; ++so) {
        const size_t nso = (size_t)(n * 8 + so) << 15;
        const float  u0 = U[0 * R3SZ + nso + c012];
        const float4 u1 = *(const float4*)(U + 1 * R3SZ + nso + c013);
        const float4 u2 = *(const float4*)(U + 2 * R3SZ + nso + c023);
        const float4 u3 = *(const float4*)(U + 3 * R3SZ + nso + c123);
        float4 acc;
        acc.x = u0 + u1.x + u2.x + u3.x;
        acc.y = u0 + u1.y + u2.y + u3.y;
        acc.z = u0 + u1.z + u2.z + u3.z;
        acc.w = u0 + u1.w + u2.w + u3.w;
        #pragma unroll
        for (int d = 0; d < 8; ++d) {
            const float w = c68[d * 8 + so];
            acc.x += w * xv[d].x; acc.y += w * xv[d].y;
            acc.z += w * xv[d].z; acc.w += w * xv[d].w;
        }
        *(float4*)(out + ((size_t)(n * 8 + so) << 20) + ((size_t)i << 15)
                   + j * 1024 + k * 32 + lq * 4) = acc;
    }
}

extern "C" void kernel_launch(void* const* d_in, const int* in_sizes, int n_in,
                              void* d_out, int out_size, void* d_ws, size_t ws_size,
                              hipStream_t stream) {
    const float* x     = (const float*)d_in[0];
    const float* coefs = (const float*)d_in[1];
    const float* bias  = (const float*)d_in[2];
    float* out = (float*)d_out;
    float* ws  = (float*)d_ws;

    // zero red2_23 + red1 + T2f + T1f + counters
    hipMemsetAsync((void*)(ws + R2OFF + 5 * R2SZ), 0,
                   (U3OFF - (R2OFF + 5 * R2SZ)) * sizeof(float), stream);
    hipLaunchKernelGGL(k_red3,  dim3(1024), dim3(512), 0, stream, x, coefs, ws);
    hipLaunchKernelGGL(k_mix,   dim3(1024), dim3(256), 0, stream, coefs, bias, ws);
    hipLaunchKernelGGL(k_final, dim3(2048), dim3(256), 0, stream, x, coefs, ws, out);
}